// Round 1
// 1280.261 us; speedup vs baseline: 1.1695x; 1.1695x over previous
//
#include <hip/hip_runtime.h>

// Problem: B=16, LQ=LK=1024, D=512, H=8, DK=64.
// d_out = [ out (16,1024,512) fp32 | attn (16,1024,8,1024) fp32 ]
// R1: fuse scores+softmax+PV into one flash-style kernel (saves ~1.5 GB HBM).
#define OUT_OFF 8388608ull

typedef __attribute__((ext_vector_type(4))) float f32x4;
typedef __attribute__((ext_vector_type(8))) __bf16 bf16x8;
typedef __attribute__((ext_vector_type(8))) unsigned short us8;

__device__ __forceinline__ unsigned short f2b(float f) {
  return __builtin_bit_cast(unsigned short, (__bf16)f);
}
__device__ __forceinline__ float b2f(unsigned short u) {
  return (float)__builtin_bit_cast(__bf16, u);
}
__device__ __forceinline__ bf16x8 ldfrag(const unsigned short* p) {
  return __builtin_bit_cast(bf16x8, *(const us8*)p);
}
__device__ __forceinline__ bf16x8 ldsfrag(const unsigned short* base, int byte_off) {
  return __builtin_bit_cast(bf16x8, *(const us8*)((const char*)base + byte_off));
}
__device__ __forceinline__ f32x4 mfma16(bf16x8 a, bf16x8 b, f32x4 c) {
  return __builtin_amdgcn_mfma_f32_16x16x32_bf16(a, b, c, 0, 0, 0);
}
// stage 8 fp32 -> 8 bf16 (round-to-nearest hi only) into LDS
__device__ __forceinline__ void stage8_f32(unsigned short* dst, const float* src) {
  const f32x4 x = *(const f32x4*)src;
  const f32x4 y = *(const f32x4*)(src + 4);
  us8 v;
  v[0]=f2b(x[0]); v[1]=f2b(x[1]); v[2]=f2b(x[2]); v[3]=f2b(x[3]);
  v[4]=f2b(y[0]); v[5]=f2b(y[1]); v[6]=f2b(y[2]); v[7]=f2b(y[3]);
  *(us8*)dst = v;
}
// stage 8 fp32 -> hi/lo split bf16 planes in LDS
__device__ __forceinline__ void stage8_split(unsigned short* dh, unsigned short* dl, const float* src) {
  const f32x4 x = *(const f32x4*)src;
  const f32x4 y = *(const f32x4*)(src + 4);
  us8 h, l;
  #pragma unroll
  for (int i = 0; i < 4; ++i) {
    unsigned short hv = f2b(x[i]); h[i] = hv; l[i] = f2b(x[i] - b2f(hv));
  }
  #pragma unroll
  for (int i = 0; i < 4; ++i) {
    unsigned short hv = f2b(y[i]); h[4+i] = hv; l[4+i] = f2b(y[i] - b2f(hv));
  }
  *(us8*)dh = h; *(us8*)dl = l;
}
__device__ __forceinline__ void stage8_bf(unsigned short* dst, const unsigned short* src) {
  *(us8*)dst = *(const us8*)src;
}

// ---------------- weight repack ---------------------------------------------
// Wq/Wk/Wsat/Wts (h,d,dk) -> hi/lo bf16 planes [n=h*64+dk][d]; Wv,Wh -> fp32 NxK
__global__ __launch_bounds__(256) void repack_kernel(
    const float* __restrict__ Wq, const float* __restrict__ Wk,
    const float* __restrict__ Wsat, const float* __restrict__ Wts,
    const float* __restrict__ Wv, const float* __restrict__ Wh,
    unsigned short* __restrict__ Wq_h, unsigned short* __restrict__ Wq_l,
    unsigned short* __restrict__ Wk_h, unsigned short* __restrict__ Wk_l,
    unsigned short* __restrict__ Wsat_h, unsigned short* __restrict__ Wsat_l,
    unsigned short* __restrict__ Wts_h, unsigned short* __restrict__ Wts_l,
    float* __restrict__ Wv_t, float* __restrict__ Wh_t)
{
  int i = blockIdx.x * 256 + threadIdx.x;           // 0 .. 1114111
  if (i < 1048576) {
    int seg = i >> 18, j = i & 262143;
    int n = j >> 9, d = j & 511;
    const float* W = (seg == 0) ? Wq : (seg == 1) ? Wk : (seg == 2) ? Wsat : Wts;
    unsigned short* Oh = (seg == 0) ? Wq_h : (seg == 1) ? Wk_h : (seg == 2) ? Wsat_h : Wts_h;
    unsigned short* Ol = (seg == 0) ? Wq_l : (seg == 1) ? Wk_l : (seg == 2) ? Wsat_l : Wts_l;
    float w = W[((n >> 6) * 512 + d) * 64 + (n & 63)];
    unsigned short h = f2b(w);
    Oh[j] = h; Ol[j] = f2b(w - b2f(h));
  } else if (i < 1081344) {                          // Wv_t[dk][d] = Wv[d][dk]
    int j = i - 1048576; int dk = j >> 9, d = j & 511;
    Wv_t[j] = Wv[d * 64 + dk];
  } else if (i < 1114112) {                          // Wh_t[d][dk] = Wh[dk][d]
    int j = i - 1081344; int d = j >> 6, dk = j & 63;
    Wh_t[j] = Wh[dk * 512 + d];
  }
}

// ---------------- layernorm -> hi/lo bf16 planes ----------------------------
__global__ __launch_bounds__(256) void ln_kernel(
    const float* __restrict__ sat, const float* __restrict__ ts,
    const float* __restrict__ gs, const float* __restrict__ bs,
    const float* __restrict__ gt, const float* __restrict__ bt,
    unsigned short* __restrict__ sat_h, unsigned short* __restrict__ sat_l,
    unsigned short* __restrict__ ts_h, unsigned short* __restrict__ ts_l)
{
  int row = blockIdx.x;
  const float* x; unsigned short *yh, *yl; const float* g; const float* bb;
  if (row < 16384) {
    x = sat + (size_t)row * 512; yh = sat_h + (size_t)row * 512; yl = sat_l + (size_t)row * 512;
    g = gs; bb = bs;
  } else {
    int r = row - 16384;
    x = ts + (size_t)r * 512; yh = ts_h + (size_t)r * 512; yl = ts_l + (size_t)r * 512;
    g = gt; bb = bt;
  }
  int t = threadIdx.x;
  float x0 = x[t], x1 = x[t + 256];
  float s = x0 + x1, s2 = x0 * x0 + x1 * x1;
  #pragma unroll
  for (int o = 1; o < 64; o <<= 1) { s += __shfl_xor(s, o); s2 += __shfl_xor(s2, o); }
  __shared__ float red[8];
  int w = t >> 6;
  if ((t & 63) == 0) { red[w] = s; red[4 + w] = s2; }
  __syncthreads();
  float S  = red[0] + red[1] + red[2] + red[3];
  float S2 = red[4] + red[5] + red[6] + red[7];
  float mean = S * (1.f / 512.f);
  float inv = rsqrtf(S2 * (1.f / 512.f) - mean * mean + 1e-5f);
  float y0 = (x0 - mean) * inv * g[t]       + bb[t];
  float y1 = (x1 - mean) * inv * g[t + 256] + bb[t + 256];
  unsigned short h0 = f2b(y0), h1 = f2b(y1);
  yh[t] = h0;       yl[t] = f2b(y0 - b2f(h0));
  yh[t + 256] = h1; yl[t + 256] = f2b(y1 - b2f(h1));
}

// ---------------- fused triple-GEMM + RoPE for q / k (split precision) ------
// out = rope(X@Wm + bm, Xs@Wr + br, Xc@Wr + br) stored as hi/lo bf16 planes
__global__ __launch_bounds__(256) void proj_rope_kernel(
    const unsigned short* __restrict__ Axm_h, const unsigned short* __restrict__ Axm_l,
    const float* __restrict__ Axs, const float* __restrict__ Axc,
    const unsigned short* __restrict__ Bm_h, const unsigned short* __restrict__ Bm_l,
    const unsigned short* __restrict__ Br_h, const unsigned short* __restrict__ Br_l,
    const float* __restrict__ bm_, const float* __restrict__ br_,
    unsigned short* __restrict__ out_h, unsigned short* __restrict__ out_l)
{
  __shared__ __attribute__((aligned(16))) unsigned short
      sAmH[64*40], sAmL[64*40], sAsH[64*40], sAsL[64*40], sAcH[64*40], sAcL[64*40],
      sBmH[64*40], sBmL[64*40], sBrH[64*40], sBrL[64*40];
  const int tid = threadIdx.x;
  const int lane = tid & 63, wid = tid >> 6;
  const int wy = wid >> 1, wx = wid & 1;
  const int m0 = blockIdx.x * 64, n0 = blockIdx.y * 64;
  const int srow = tid >> 2, sc8 = (tid & 3) * 8;
  const int sidx = srow * 40 + sc8;

  f32x4 accM[2][2] = {}, accS[2][2] = {}, accC[2][2] = {};

  for (int k0 = 0; k0 < 512; k0 += 32) {
    const size_t ao = (size_t)(m0 + srow) * 512 + k0 + sc8;
    stage8_bf(&sAmH[sidx], Axm_h + ao);
    stage8_bf(&sAmL[sidx], Axm_l + ao);
    stage8_split(&sAsH[sidx], &sAsL[sidx], Axs + ao);
    stage8_split(&sAcH[sidx], &sAcL[sidx], Axc + ao);
    const size_t bo = (size_t)(n0 + srow) * 512 + k0 + sc8;
    stage8_bf(&sBmH[sidx], Bm_h + bo);
    stage8_bf(&sBmL[sidx], Bm_l + bo);
    stage8_bf(&sBrH[sidx], Br_h + bo);
    stage8_bf(&sBrL[sidx], Br_l + bo);
    __syncthreads();
    const int q8 = (lane >> 4) * 8;
    const int fm = (wy * 32 + (lane & 15)) * 40 + q8;
    const int fn = (wx * 32 + (lane & 15)) * 40 + q8;
    bf16x8 amh0 = ldfrag(&sAmH[fm]), amh1 = ldfrag(&sAmH[fm + 640]);
    bf16x8 aml0 = ldfrag(&sAmL[fm]), aml1 = ldfrag(&sAmL[fm + 640]);
    bf16x8 ash0 = ldfrag(&sAsH[fm]), ash1 = ldfrag(&sAsH[fm + 640]);
    bf16x8 asl0 = ldfrag(&sAsL[fm]), asl1 = ldfrag(&sAsL[fm + 640]);
    bf16x8 ach0 = ldfrag(&sAcH[fm]), ach1 = ldfrag(&sAcH[fm + 640]);
    bf16x8 acl0 = ldfrag(&sAcL[fm]), acl1 = ldfrag(&sAcL[fm + 640]);
    bf16x8 bmh0 = ldfrag(&sBmH[fn]), bmh1 = ldfrag(&sBmH[fn + 640]);
    bf16x8 bml0 = ldfrag(&sBmL[fn]), bml1 = ldfrag(&sBmL[fn + 640]);
    bf16x8 brh0 = ldfrag(&sBrH[fn]), brh1 = ldfrag(&sBrH[fn + 640]);
    bf16x8 brl0 = ldfrag(&sBrL[fn]), brl1 = ldfrag(&sBrL[fn + 640]);
    // main: hi*hi + hi*lo + lo*hi
    accM[0][0] = mfma16(amh0, bmh0, accM[0][0]); accM[0][1] = mfma16(amh0, bmh1, accM[0][1]);
    accM[1][0] = mfma16(amh1, bmh0, accM[1][0]); accM[1][1] = mfma16(amh1, bmh1, accM[1][1]);
    accM[0][0] = mfma16(amh0, bml0, accM[0][0]); accM[0][1] = mfma16(amh0, bml1, accM[0][1]);
    accM[1][0] = mfma16(amh1, bml0, accM[1][0]); accM[1][1] = mfma16(amh1, bml1, accM[1][1]);
    accM[0][0] = mfma16(aml0, bmh0, accM[0][0]); accM[0][1] = mfma16(aml0, bmh1, accM[0][1]);
    accM[1][0] = mfma16(aml1, bmh0, accM[1][0]); accM[1][1] = mfma16(aml1, bmh1, accM[1][1]);
    // sin
    accS[0][0] = mfma16(ash0, brh0, accS[0][0]); accS[0][1] = mfma16(ash0, brh1, accS[0][1]);
    accS[1][0] = mfma16(ash1, brh0, accS[1][0]); accS[1][1] = mfma16(ash1, brh1, accS[1][1]);
    accS[0][0] = mfma16(ash0, brl0, accS[0][0]); accS[0][1] = mfma16(ash0, brl1, accS[0][1]);
    accS[1][0] = mfma16(ash1, brl0, accS[1][0]); accS[1][1] = mfma16(ash1, brl1, accS[1][1]);
    accS[0][0] = mfma16(asl0, brh0, accS[0][0]); accS[0][1] = mfma16(asl0, brh1, accS[0][1]);
    accS[1][0] = mfma16(asl1, brh0, accS[1][0]); accS[1][1] = mfma16(asl1, brh1, accS[1][1]);
    // cos
    accC[0][0] = mfma16(ach0, brh0, accC[0][0]); accC[0][1] = mfma16(ach0, brh1, accC[0][1]);
    accC[1][0] = mfma16(ach1, brh0, accC[1][0]); accC[1][1] = mfma16(ach1, brh1, accC[1][1]);
    accC[0][0] = mfma16(ach0, brl0, accC[0][0]); accC[0][1] = mfma16(ach0, brl1, accC[0][1]);
    accC[1][0] = mfma16(ach1, brl0, accC[1][0]); accC[1][1] = mfma16(ach1, brl1, accC[1][1]);
    accC[0][0] = mfma16(acl0, brh0, accC[0][0]); accC[0][1] = mfma16(acl0, brh1, accC[0][1]);
    accC[1][0] = mfma16(acl1, brh0, accC[1][0]); accC[1][1] = mfma16(acl1, brh1, accC[1][1]);
    __syncthreads();
  }

  const int col = lane & 15, quad = lane >> 4;
  #pragma unroll
  for (int nt = 0; nt < 2; ++nt) {
    const int n = n0 + wx * 32 + nt * 16 + col;
    const float bmv = bm_[n], brv = br_[n];
    const int h = n >> 6, dk = n & 63;
    const float sgn = (n & 1) ? 1.f : -1.f;   // even dk: -q[dk+1]*sin, odd dk: +q[dk-1]*sin
    #pragma unroll
    for (int mt = 0; mt < 2; ++mt) {
      #pragma unroll
      for (int r = 0; r < 4; ++r) {
        float qv = accM[mt][nt][r] + bmv;
        float sv = accS[mt][nt][r] + brv;
        float cv = accC[mt][nt][r] + brv;
        float qo = __shfl_xor(qv, 1);         // paired dk column lives in lane^1
        float res = qv * cv + sgn * qo * sv;
        const int m = m0 + wy * 32 + mt * 16 + quad * 4 + r;
        const int b = m >> 10, l = m & 1023;
        const size_t idx = (((size_t)(b * 8 + h) * 1024 + l) << 6) + dk;
        unsigned short hv = f2b(res);
        out_h[idx] = hv;
        out_l[idx] = f2b(res - b2f(hv));
      }
    }
  }
}

// ---------------- fused scores + softmax + attn-write + PV ------------------
// One block = one (b,h) x 16 q-rows. Full 1024-wide score row held in regs
// (wave w owns n-tile w of each 64-col chunk -> 16 f32x4 per lane).
// K tiles reg-staged into XOR-swizzled LDS (T14 issue-early). P -> bf16 LDS
// (swizzled) feeds PV MFMA with V-fragments straight from L2-resident vt.
__global__ __launch_bounds__(256) void fused_attn_kernel(
    const unsigned short* __restrict__ q_h, const unsigned short* __restrict__ q_l,
    const unsigned short* __restrict__ k_h, const unsigned short* __restrict__ k_l,
    const unsigned short* __restrict__ vt,
    float* __restrict__ attn, float* __restrict__ out_pre)
{
  __shared__ __attribute__((aligned(16))) unsigned short sK[8192];   // 2 planes x [64 rows][8 slots x 16B], swizzled
  __shared__ __attribute__((aligned(16))) unsigned short sP[16384];  // [16 rows][1024] bf16, swizzled
  __shared__ float redM[16][4];
  __shared__ float redS[16][4];

  const int tid  = threadIdx.x;
  const int lane = tid & 63, wid = tid >> 6;
  const int col  = lane & 15, quad = lane >> 4;
  const int q0   = blockIdx.x * 16;
  const int z    = blockIdx.y;                 // b*8 + h
  const int b    = z >> 3;
  const size_t zoff = (size_t)z << 16;         // 1024*64 elems per (b,h)

  // ---- Q fragments straight from global (A-frag layout: row=col, k=quad*8+j)
  const size_t qoff = zoff + (size_t)(q0 + col) * 64 + quad * 8;
  const bf16x8 aQh0 = ldfrag(q_h + qoff), aQh1 = ldfrag(q_h + qoff + 32);
  const bf16x8 aQl0 = ldfrag(q_l + qoff), aQl1 = ldfrag(q_l + qoff + 32);

  // ---- K staging plan: slot s = tid + i*256; plane = s>>9, row=(s>>3)&63, c16=s&7
  // LDS byte = plane*8192 + row*128 + ((c16 ^ (row&7))<<4)  (write & read both swizzled)
  us8 kreg[4];
  const unsigned short* ksrc[4];
  int kdst[4];
  #pragma unroll
  for (int i = 0; i < 4; ++i) {
    const int s = tid + i * 256;
    const int plane = s >> 9, r = (s >> 3) & 63, c = s & 7;
    ksrc[i] = (plane ? k_l : k_h) + zoff + (size_t)r * 64 + c * 8;
    kdst[i] = plane * 8192 + r * 128 + ((c ^ (r & 7)) << 4);
  }
  #pragma unroll
  for (int i = 0; i < 4; ++i) kreg[i] = *(const us8*)(ksrc[i]);   // kt = 0

  // B-fragment LDS offsets (constant across kt; sK is reused per tile)
  const int nl  = wid * 16 + col;            // local key row 0..63
  const int sx  = nl & 7;
  const int bh0_off = nl * 128 + ((quad ^ sx) << 4);
  const int bh1_off = nl * 128 + (((4 + quad) ^ sx) << 4);
  const int bl0_off = 8192 + bh0_off;
  const int bl1_off = 8192 + bh1_off;

  f32x4 acc[16];
  #pragma unroll
  for (int kt = 0; kt < 16; ++kt) acc[kt] = (f32x4){0.f, 0.f, 0.f, 0.f};

  // ---- QK^T over 16 key tiles of 64
  #pragma unroll
  for (int kt = 0; kt < 16; ++kt) {
    __syncthreads();                                   // prior tile's reads done
    #pragma unroll
    for (int i = 0; i < 4; ++i) *(us8*)((char*)sK + kdst[i]) = kreg[i];
    __syncthreads();                                   // sK ready
    if (kt < 15) {
      #pragma unroll
      for (int i = 0; i < 4; ++i) kreg[i] = *(const us8*)(ksrc[i] + (kt + 1) * 4096);
    }
    bf16x8 bh0 = ldsfrag(sK, bh0_off), bh1 = ldsfrag(sK, bh1_off);
    bf16x8 bl0 = ldsfrag(sK, bl0_off), bl1 = ldsfrag(sK, bl1_off);
    acc[kt] = mfma16(aQh0, bh0, acc[kt]);
    acc[kt] = mfma16(aQh0, bl0, acc[kt]);
    acc[kt] = mfma16(aQl0, bh0, acc[kt]);
    acc[kt] = mfma16(aQh1, bh1, acc[kt]);
    acc[kt] = mfma16(aQh1, bl1, acc[kt]);
    acc[kt] = mfma16(aQl1, bh1, acc[kt]);
  }

  // ---- softmax over full row (exact max, fp32), rows = quad*4 + r
  float pm[4];
  #pragma unroll
  for (int r = 0; r < 4; ++r) pm[r] = acc[0][r];
  #pragma unroll
  for (int kt = 1; kt < 16; ++kt)
    #pragma unroll
    for (int r = 0; r < 4; ++r) pm[r] = fmaxf(pm[r], acc[kt][r]);
  #pragma unroll
  for (int o = 1; o < 16; o <<= 1)
    #pragma unroll
    for (int r = 0; r < 4; ++r) pm[r] = fmaxf(pm[r], __shfl_xor(pm[r], o));
  if (col == 0)
    #pragma unroll
    for (int r = 0; r < 4; ++r) redM[quad * 4 + r][wid] = pm[r];
  __syncthreads();
  float M_[4];
  #pragma unroll
  for (int r = 0; r < 4; ++r) {
    const float* q = redM[quad * 4 + r];
    M_[r] = fmaxf(fmaxf(q[0], q[1]), fmaxf(q[2], q[3]));
  }
  float ps[4] = {0.f, 0.f, 0.f, 0.f};
  #pragma unroll
  for (int kt = 0; kt < 16; ++kt)
    #pragma unroll
    for (int r = 0; r < 4; ++r) {
      float p = __expf((acc[kt][r] - M_[r]) * 0.125f);   // scores scale folded in
      acc[kt][r] = p; ps[r] += p;
    }
  #pragma unroll
  for (int o = 1; o < 16; o <<= 1)
    #pragma unroll
    for (int r = 0; r < 4; ++r) ps[r] += __shfl_xor(ps[r], o);
  if (col == 0)
    #pragma unroll
    for (int r = 0; r < 4; ++r) redS[quad * 4 + r][wid] = ps[r];
  __syncthreads();
  float rinv[4];
  #pragma unroll
  for (int r = 0; r < 4; ++r) {
    const float* q = redS[quad * 4 + r];
    rinv[r] = 1.f / (q[0] + q[1] + q[2] + q[3]);
  }

  // ---- write normalized attn (mandatory output) + stage P bf16 into LDS
  const size_t arow = ((((size_t)b << 10) + q0) * 8 + (z & 7)) << 10;
  #pragma unroll
  for (int kt = 0; kt < 16; ++kt) {
    const int cg = kt * 64 + wid * 16 + col;
    #pragma unroll
    for (int r = 0; r < 4; ++r) {
      const int row = quad * 4 + r;
      const float pn = acc[kt][r] * rinv[r];
      attn[arow + (size_t)row * 8192 + cg] = pn;
      *(unsigned short*)((char*)sP + ((row * 2048 + cg * 2) ^ ((row & 7) << 4))) = f2b(pn);
    }
  }
  __syncthreads();

  // ---- PV: C[16 q-rows][16 dk] per wave; A = P from LDS, B = vt from global
  f32x4 o4 = (f32x4){0.f, 0.f, 0.f, 0.f};
  const unsigned short* vb = vt + ((size_t)b << 16) + (size_t)(wid * 16 + col) * 1024;
  const int prow = col * 2048;
  const int pswz = (col & 7) << 4;
  #pragma unroll 4
  for (int k0 = 0; k0 < 1024; k0 += 32) {
    bf16x8 a  = ldsfrag(sP, prow + (((k0 + quad * 8) * 2) ^ pswz));
    bf16x8 bv = ldfrag(vb + k0 + quad * 8);
    o4 = mfma16(a, bv, o4);
  }
  const size_t obase = ((size_t)b << 16) + (size_t)(q0 + quad * 4) * 64 + wid * 16 + col;
  #pragma unroll
  for (int r = 0; r < 4; ++r) atomicAdd(&out_pre[obase + (size_t)r * 64], o4[r]);
}

// ---------------- generic MFMA GEMM (TN) ------------------------------------
enum { MODE_V = 0, MODE_OUT = 3 };

template<int MODE>
__global__ __launch_bounds__(256) void mfma_gemm(
    const void* __restrict__ Ap, const void* __restrict__ Bp,
    const float* __restrict__ bias, void* __restrict__ Outp)
{
  constexpr bool A_BF  = (MODE == MODE_V);
  constexpr int  LDA   = (MODE == MODE_V) ? 512 : 64;
  constexpr int  LDB   = (MODE == MODE_V) ? 512 : 64;
  constexpr int  KTOT  = (MODE == MODE_V) ? 512 : 64;
  constexpr float SCALE = (MODE == MODE_V) ? 0.125f : 1.0f;

  __shared__ __attribute__((aligned(16))) unsigned short sA[64*40], sB[64*40];
  const int tid = threadIdx.x;
  const int lane = tid & 63, wid = tid >> 6;
  const int wy = wid >> 1, wx = wid & 1;
  const int m0 = blockIdx.x * 64, n0 = blockIdx.y * 64;
  const int srow = tid >> 2, sc8 = (tid & 3) * 8;
  const int sidx = srow * 40 + sc8;

  const float* Af = (const float*)Ap;  const unsigned short* Ab = (const unsigned short*)Ap;
  const float* Bf = (const float*)Bp;

  f32x4 acc[2][2] = {};

  for (int k0 = 0; k0 < KTOT; k0 += 32) {
    { const size_t ao = (size_t)(m0 + srow) * LDA + k0 + sc8;
      if constexpr (A_BF) stage8_bf(&sA[sidx], Ab + ao); else stage8_f32(&sA[sidx], Af + ao); }
    { const size_t bo = (size_t)(n0 + srow) * LDB + k0 + sc8;
      stage8_f32(&sB[sidx], Bf + bo); }
    __syncthreads();
    const int q8 = (lane >> 4) * 8;
    const int fm = (wy * 32 + (lane & 15)) * 40 + q8;
    const int fn = (wx * 32 + (lane & 15)) * 40 + q8;
    bf16x8 a0 = ldfrag(&sA[fm]), a1 = ldfrag(&sA[fm + 640]);
    bf16x8 b0 = ldfrag(&sB[fn]), b1 = ldfrag(&sB[fn + 640]);
    acc[0][0] = mfma16(a0, b0, acc[0][0]); acc[0][1] = mfma16(a0, b1, acc[0][1]);
    acc[1][0] = mfma16(a1, b0, acc[1][0]); acc[1][1] = mfma16(a1, b1, acc[1][1]);
    __syncthreads();
  }

  const int col = lane & 15, quad = lane >> 4;
  #pragma unroll
  for (int nt = 0; nt < 2; ++nt) {
    const int n = n0 + wx * 32 + nt * 16 + col;
    const float bv = bias ? bias[n] : 0.f;
    #pragma unroll
    for (int mt = 0; mt < 2; ++mt) {
      #pragma unroll
      for (int r = 0; r < 4; ++r) {
        const int m = m0 + wy * 32 + mt * 16 + quad * 4 + r;
        const float v = (acc[mt][nt][r] + bv) * SCALE;
        if constexpr (MODE == MODE_V) {
          // vt[b][dk=n][l] bf16, includes bias and 1/H scale
          ((unsigned short*)Outp)[((size_t)(m >> 10) << 16) + ((size_t)n << 10) + (m & 1023)] = f2b(v);
        } else { // MODE_OUT: d_out (b,l,d) row-major
          ((float*)Outp)[(size_t)m * 512 + n] = v;
        }
      }
    }
  }
}

// ---------------------------------------------------------------------------
extern "C" void kernel_launch(void* const* d_in, const int* in_sizes, int n_in,
                              void* d_out, int out_size, void* d_ws, size_t ws_size,
                              hipStream_t stream)
{
  const float* satellite  = (const float*)d_in[0];
  const float* sat_pos    = (const float*)d_in[1];
  const float* timeseries = (const float*)d_in[2];
  const float* ts_pos     = (const float*)d_in[3];
  const float* ln_sat_g   = (const float*)d_in[4];
  const float* ln_sat_b   = (const float*)d_in[5];
  const float* ln_ts_g    = (const float*)d_in[6];
  const float* ln_ts_b    = (const float*)d_in[7];
  const float* Wv  = (const float*)d_in[8];
  const float* bv  = (const float*)d_in[9];
  const float* Wq  = (const float*)d_in[10];
  const float* bq  = (const float*)d_in[11];
  const float* Wk  = (const float*)d_in[12];
  const float* bk  = (const float*)d_in[13];
  const float* Wsat= (const float*)d_in[14];
  const float* bsat= (const float*)d_in[15];
  const float* Wts = (const float*)d_in[16];
  const float* bts = (const float*)d_in[17];
  const float* Wh  = (const float*)d_in[18];

  char* ws = (char*)d_ws;
  unsigned short* sat_h = (unsigned short*)(ws + 0);          // 16.78 MB each
  unsigned short* sat_l = (unsigned short*)(ws + 16777216);
  unsigned short* ts_h  = (unsigned short*)(ws + 33554432);
  unsigned short* ts_l  = (unsigned short*)(ws + 50331648);
  unsigned short* q_hi  = (unsigned short*)(ws + 67108864);   // (b,h,l,dk) bf16 hi plane
  unsigned short* k_hi  = (unsigned short*)(ws + 83886080);
  unsigned short* vt    = (unsigned short*)(ws + 100663296);  // 2.10 MB bf16 (b,dk,l), 1/H pre-scaled
  float* out_pre        = (float*)(ws + 102760448);           // 4.19 MB
  char* wb = ws + 106954752;
  unsigned short* Wq_h   = (unsigned short*)(wb + 0);
  unsigned short* Wq_l   = (unsigned short*)(wb + 524288);
  unsigned short* Wk_h   = (unsigned short*)(wb + 1048576);
  unsigned short* Wk_l   = (unsigned short*)(wb + 1572864);
  unsigned short* Wsat_h = (unsigned short*)(wb + 2097152);
  unsigned short* Wsat_l = (unsigned short*)(wb + 2621440);
  unsigned short* Wts_h  = (unsigned short*)(wb + 3145728);
  unsigned short* Wts_l  = (unsigned short*)(wb + 3670016);
  float* Wv_t            = (float*)(wb + 4194304);
  float* Wh_t            = (float*)(wb + 4325376);            // end ~111.4 MB

  float* outF = (float*)d_out;
  float* attn = outF + OUT_OFF;
  // lo planes of q/k live in the (not-yet-written) `out` region of d_out;
  // they are dead by the time MODE_OUT overwrites it.
  unsigned short* q_lo = (unsigned short*)d_out;
  unsigned short* k_lo = (unsigned short*)d_out + 8388608;

  repack_kernel<<<4352, 256, 0, stream>>>(Wq, Wk, Wsat, Wts, Wv, Wh,
      Wq_h, Wq_l, Wk_h, Wk_l, Wsat_h, Wsat_l, Wts_h, Wts_l, Wv_t, Wh_t);
  ln_kernel<<<32768, 256, 0, stream>>>(satellite, timeseries, ln_sat_g, ln_sat_b,
                                       ln_ts_g, ln_ts_b, sat_h, sat_l, ts_h, ts_l);
  // q = rope(ts_ln@Wq+bq, ts_pos0@Wts+bts, ts_pos1@Wts+bts)
  proj_rope_kernel<<<dim3(256, 8), 256, 0, stream>>>(
      ts_h, ts_l, ts_pos, ts_pos + 8388608, Wq_h, Wq_l, Wts_h, Wts_l, bq, bts, q_hi, q_lo);
  // k = rope(sat_ln@Wk+bk, sat_pos0@Wsat+bsat, sat_pos1@Wsat+bsat)
  proj_rope_kernel<<<dim3(256, 8), 256, 0, stream>>>(
      sat_h, sat_l, sat_pos, sat_pos + 8388608, Wk_h, Wk_l, Wsat_h, Wsat_l, bk, bsat, k_hi, k_lo);
  mfma_gemm<MODE_V><<<dim3(256, 1, 1), 256, 0, stream>>>(sat_h, Wv_t, bv, vt);
  hipMemsetAsync(out_pre, 0, 16384 * 64 * 4, stream);
  // fused scores -> softmax -> attn write -> PV (replaces 3 kernels, -1.5 GB HBM)
  fused_attn_kernel<<<dim3(64, 128), 256, 0, stream>>>(
      q_hi, q_lo, k_hi, k_lo, vt, attn, out_pre);
  mfma_gemm<MODE_OUT><<<dim3(256, 8, 1), 256, 0, stream>>>(out_pre, Wh_t, nullptr, outF);
}